// Round 1
// baseline (576.923 us; speedup 1.0000x reference)
//
#include <hip/hip_runtime.h>
#include <hip/hip_bf16.h>

typedef __bf16 bf16x8 __attribute__((ext_vector_type(8)));
typedef float f32x4 __attribute__((ext_vector_type(4)));

__device__ __forceinline__ void gload16(const void* g, void* l) {
  __builtin_amdgcn_global_load_lds(
      (const __attribute__((address_space(1))) unsigned int*)g,
      (__attribute__((address_space(3))) unsigned int*)l, 16, 0, 0);
}

__device__ __forceinline__ float gelu_f(float x) {
  return 0.5f * x * (1.f + erff(x * 0.70710678118654752f));
}
__device__ __forceinline__ float sigmoid_f(float x) {
  return 1.f / (1.f + __expf(-x));
}

// ---------------------------------------------------------------------------
// Generic bf16 GEMM: C[m,n] = sum_k A[m,k] * B[n,k] (+bias[n]) with epilogues.
// Block: 256 thr (4 waves), tile 128x128, BK=32, m97 structure.
// EPI: 0 = plain, 1 = gelu, 2 = gate-fusion (paired 16-col gate/trans chunks)
// ---------------------------------------------------------------------------
template<int EPI, bool OBF16>
__global__ __launch_bounds__(256)
void gemm_kernel(const __hip_bfloat16* __restrict__ A, int lda,
                 const __hip_bfloat16* __restrict__ B, int ldb,
                 const float* __restrict__ bias,
                 const float* __restrict__ rowscale,
                 void* __restrict__ C, int ldc, int K)
{
  __shared__ __align__(16) __hip_bfloat16 As[128 * 32];
  __shared__ __align__(16) __hip_bfloat16 Bs[128 * 32];
  const int t = threadIdx.x;
  const int l = t & 63, w = t >> 6;
  const int m0 = blockIdx.y * 128, n0 = blockIdx.x * 128;
  const int wm = (w >> 1) * 64, wn = (w & 1) * 64;
  const int l15 = l & 15, lg = l >> 4;
  f32x4 acc[4][4] = {};
  const int r0 = t >> 2;            // staging row within first 64
  const int kk0 = (t & 3) * 8;      // k sub-offset
  const size_t arow = (size_t)(m0 + r0) * lda + kk0;
  const size_t arow2 = (size_t)(m0 + r0 + 64) * lda + kk0;
  const size_t brow = (size_t)(n0 + r0) * ldb + kk0;
  const size_t brow2 = (size_t)(n0 + r0 + 64) * ldb + kk0;
  char* lA = (char*)As + t * 16;
  char* lB = (char*)Bs + t * 16;
  for (int k0 = 0; k0 < K; k0 += 32) {
    gload16(A + arow + k0, lA);
    gload16(A + arow2 + k0, lA + 4096);
    gload16(B + brow + k0, lB);
    gload16(B + brow2 + k0, lB + 4096);
    __syncthreads();
    bf16x8 af[4], bfr[4];
    const int lk = lg * 8;
#pragma unroll
    for (int i = 0; i < 4; ++i) {
      af[i]  = *(const bf16x8*)((const __hip_bfloat16*)As + (wm + i * 16 + l15) * 32 + lk);
      bfr[i] = *(const bf16x8*)((const __hip_bfloat16*)Bs + (wn + i * 16 + l15) * 32 + lk);
    }
#pragma unroll
    for (int mi = 0; mi < 4; ++mi)
#pragma unroll
      for (int ni = 0; ni < 4; ++ni)
        acc[mi][ni] = __builtin_amdgcn_mfma_f32_16x16x32_bf16(af[mi], bfr[ni], acc[mi][ni], 0, 0, 0);
    __syncthreads();
  }

  if (EPI == 2) {
    // gate fusion: even frag = gate chunk, odd frag = matching trans chunk
#pragma unroll
    for (int mi = 0; mi < 4; ++mi) {
#pragma unroll
      for (int nh = 0; nh < 2; ++nh) {
        const int ni = nh * 2;
        const int sc = n0 + wn + ni * 16;      // stacked col base
        const float bg = bias[sc + l15];
        const float bt = bias[sc + 16 + l15];
        const int ocol = (sc >> 5) * 16 + l15;
#pragma unroll
        for (int j = 0; j < 4; ++j) {
          const int row = m0 + wm + mi * 16 + lg * 4 + j;
          float g = acc[mi][ni][j] + bg;
          float tv = acc[mi][ni + 1][j] + bt;
          ((float*)C)[(size_t)row * ldc + ocol] = sigmoid_f(g) * gelu_f(tv);
        }
      }
    }
    return;
  }
#pragma unroll
  for (int mi = 0; mi < 4; ++mi)
#pragma unroll
    for (int ni = 0; ni < 4; ++ni) {
      const int col = n0 + wn + ni * 16 + l15;
      const float bc = bias ? bias[col] : 0.f;
#pragma unroll
      for (int j = 0; j < 4; ++j) {
        const int row = m0 + wm + mi * 16 + lg * 4 + j;
        float v = acc[mi][ni][j] + bc;
        if (EPI == 1) v = gelu_f(v);
        if (rowscale) v *= rowscale[row];
        if (OBF16) ((__hip_bfloat16*)C)[(size_t)row * ldc + col] = __float2bfloat16(v);
        else       ((float*)C)[(size_t)row * ldc + col] = v;
      }
    }
}

// ---------------------------------------------------------------------------
// Attention, one block per (b, head). Full 128x128 score tile.
// SIB=false: head-attn (K/V gathered by pred_heads), no mask.
// SIB=true : sibling attn with allowed mask + per-row flag output.
// ---------------------------------------------------------------------------
template<bool SIB>
__global__ __launch_bounds__(256)
void attn_kernel(const __hip_bfloat16* __restrict__ QKV,
                 const int* __restrict__ pred_heads,
                 const int* __restrict__ mask,
                 __hip_bfloat16* __restrict__ Oout,
                 float* __restrict__ flags,
                 int qofs)
{
  __shared__ __align__(16) __hip_bfloat16 smem[128 * 128];  // Q|K, later P
  __shared__ __align__(16) __hip_bfloat16 Vt[64 * 128];     // V transposed
  __shared__ int hs[128];
  __shared__ int mk[128];
  const int b = blockIdx.x >> 3, h = blockIdx.x & 7;
  const int t = threadIdx.x, l = t & 63, w = t >> 6;
  const int l15 = l & 15, lg = l >> 4;
  __hip_bfloat16* Qs = smem;
  __hip_bfloat16* Ks = smem + 128 * 64;

  if (t < 128) {
    int hh = pred_heads[b * 128 + t];
    hh = hh < 0 ? 0 : (hh > 127 ? 127 : hh);
    hs[t] = hh;
    mk[t] = mask[b * 128 + t];
  }
  __syncthreads();
  const size_t tb = (size_t)b * 128 * 3072;
  const int co = qofs + h * 64;
#pragma unroll
  for (int it = 0; it < 4; ++it) {
    int idx = it * 256 + t;
    int row = idx >> 3;
    int c8 = (idx & 7) * 8;
    *(uint4*)(Qs + row * 64 + c8) = *(const uint4*)(QKV + tb + (size_t)row * 3072 + co + c8);
    int krow = SIB ? row : hs[row];
    *(uint4*)(Ks + row * 64 + c8) = *(const uint4*)(QKV + tb + (size_t)krow * 3072 + co + 512 + c8);
    uint4 vv = *(const uint4*)(QKV + tb + (size_t)krow * 3072 + co + 1024 + c8);
    const __hip_bfloat16* vp = (const __hip_bfloat16*)&vv;
#pragma unroll
    for (int u = 0; u < 8; ++u) Vt[(c8 + u) * 128 + row] = vp[u];
  }
  __syncthreads();

  const int r0 = w * 32;
  f32x4 s[2][8] = {};
#pragma unroll
  for (int ks = 0; ks < 2; ++ks) {
    const int lk = ks * 32 + lg * 8;
    bf16x8 qa0 = *(const bf16x8*)(Qs + (r0 + l15) * 64 + lk);
    bf16x8 qa1 = *(const bf16x8*)(Qs + (r0 + 16 + l15) * 64 + lk);
#pragma unroll
    for (int nj = 0; nj < 8; ++nj) {
      bf16x8 kb = *(const bf16x8*)(Ks + (nj * 16 + l15) * 64 + lk);
      s[0][nj] = __builtin_amdgcn_mfma_f32_16x16x32_bf16(qa0, kb, s[0][nj], 0, 0, 0);
      s[1][nj] = __builtin_amdgcn_mfma_f32_16x16x32_bf16(qa1, kb, s[1][nj], 0, 0, 0);
    }
  }
  const float scale = 0.125f;   // 1/sqrt(64)
  float inv_sum[2][4];
#pragma unroll
  for (int mi = 0; mi < 2; ++mi) {
#pragma unroll
    for (int j = 0; j < 4; ++j) {
      const int row = r0 + mi * 16 + lg * 4 + j;
      float mx = -1e30f;
#pragma unroll
      for (int nj = 0; nj < 8; ++nj) {
        float v = s[mi][nj][j] * scale;
        bool ok = true;
        if (SIB) {
          int c = nj * 16 + l15;
          ok = (hs[row] == hs[c]) && (row != c) && mk[row] && mk[c];
        }
        mx = fmaxf(mx, ok ? v : -1e30f);
      }
#pragma unroll
      for (int m = 1; m < 16; m <<= 1) mx = fmaxf(mx, __shfl_xor(mx, m));
      float sum = 0.f;
#pragma unroll
      for (int nj = 0; nj < 8; ++nj) {
        float v = s[mi][nj][j] * scale;
        bool ok = true;
        if (SIB) {
          int c = nj * 16 + l15;
          ok = (hs[row] == hs[c]) && (row != c) && mk[row] && mk[c];
        }
        float p = ok ? __expf(v - mx) : 0.f;
        s[mi][nj][j] = p;
        sum += p;
      }
#pragma unroll
      for (int m = 1; m < 16; m <<= 1) sum += __shfl_xor(sum, m);
      inv_sum[mi][j] = sum > 0.f ? 1.f / sum : 0.f;
    }
  }
  __syncthreads();  // all waves done reading Qs/Ks
#pragma unroll
  for (int mi = 0; mi < 2; ++mi)
#pragma unroll
    for (int nj = 0; nj < 8; ++nj)
#pragma unroll
      for (int j = 0; j < 4; ++j) {
        int row = r0 + mi * 16 + lg * 4 + j;
        int c = nj * 16 + l15;
        smem[row * 128 + c] = __float2bfloat16(s[mi][nj][j]);
      }
  __syncthreads();

  f32x4 o[2][4] = {};
#pragma unroll
  for (int js = 0; js < 4; ++js) {
    const int lk = js * 32 + lg * 8;
    bf16x8 pa0 = *(const bf16x8*)(smem + (r0 + l15) * 128 + lk);
    bf16x8 pa1 = *(const bf16x8*)(smem + (r0 + 16 + l15) * 128 + lk);
#pragma unroll
    for (int dj = 0; dj < 4; ++dj) {
      bf16x8 vb = *(const bf16x8*)(Vt + (dj * 16 + l15) * 128 + lk);
      o[0][dj] = __builtin_amdgcn_mfma_f32_16x16x32_bf16(pa0, vb, o[0][dj], 0, 0, 0);
      o[1][dj] = __builtin_amdgcn_mfma_f32_16x16x32_bf16(pa1, vb, o[1][dj], 0, 0, 0);
    }
  }
  const int hb = h * 64;
#pragma unroll
  for (int mi = 0; mi < 2; ++mi)
#pragma unroll
    for (int dj = 0; dj < 4; ++dj)
#pragma unroll
      for (int j = 0; j < 4; ++j) {
        int row = r0 + mi * 16 + lg * 4 + j;
        int dc = dj * 16 + l15;
        float val = o[mi][dj][j] * inv_sum[mi][j];
        Oout[(size_t)(b * 128 + row) * 512 + hb + dc] = __float2bfloat16(val);
      }
  if (SIB && h == 0 && l15 == 0) {
#pragma unroll
    for (int mi = 0; mi < 2; ++mi)
#pragma unroll
      for (int j = 0; j < 4; ++j) {
        int row = r0 + mi * 16 + lg * 4 + j;
        flags[b * 128 + row] = inv_sum[mi][j] > 0.f ? 1.f : 0.f;
      }
  }
}

// ---------------------------------------------------------------------------
// Child aggregation: per (64-col chunk, batch) block; LDS scatter-add tile.
// Writes child_avg (bf16) into Xc[:, 512:1024].
// ---------------------------------------------------------------------------
__global__ __launch_bounds__(256)
void child_kernel(const float* __restrict__ H,
                  const int* __restrict__ pred_heads,
                  const int* __restrict__ mask,
                  __hip_bfloat16* __restrict__ Xc)
{
  __shared__ float sum[128 * 64];
  __shared__ int cnt[128];
  __shared__ int hsl[128];
  __shared__ int vld[128];
  const int t = threadIdx.x;
  const int b = blockIdx.y, ch = blockIdx.x;  // ch in 0..7
#pragma unroll
  for (int u = 0; u < 32; ++u) sum[u * 256 + t] = 0.f;
  if (t < 128) {
    int hh = pred_heads[b * 128 + t];
    hh = hh < 0 ? 0 : (hh > 127 ? 127 : hh);
    hsl[t] = hh;
    vld[t] = (mask[b * 128 + t] != 0) && (t >= 1);
    cnt[t] = 0;
  }
  __syncthreads();
  if (t < 128 && vld[t]) atomicAdd(&cnt[hsl[t]], 1);
  __syncthreads();
  const int c = t & 63;
  const int isub = t >> 6;
  for (int ii = 0; ii < 32; ++ii) {
    int i = ii * 4 + isub;
    if (vld[i]) atomicAdd(&sum[hsl[i] * 64 + c], H[((size_t)b * 128 + i) * 512 + ch * 64 + c]);
  }
  __syncthreads();
#pragma unroll
  for (int u = 0; u < 32; ++u) {
    int idx = u * 256 + t;
    int p = idx >> 6, cc = idx & 63;
    float avg = sum[idx] / fmaxf((float)cnt[p], 1.f);
    Xc[((size_t)b * 128 + p) * 1024 + 512 + ch * 64 + cc] = __float2bfloat16(avg);
  }
}

// copy Hbf into Xc[:,0:512] and combined[:,0:512]
__global__ void pack_kernel(const __hip_bfloat16* __restrict__ Hbf,
                            __hip_bfloat16* __restrict__ Xc,
                            __hip_bfloat16* __restrict__ comb)
{
  int idx = blockIdx.x * 256 + threadIdx.x;
  int row = idx >> 6;
  int c8 = (idx & 63) * 8;
  uint4 v = *(const uint4*)(Hbf + (size_t)row * 512 + c8);
  *(uint4*)(Xc + (size_t)row * 1024 + c8) = v;
  *(uint4*)(comb + (size_t)row * 2048 + c8) = v;
}

__global__ void conv_kernel(const float* __restrict__ src,
                            __hip_bfloat16* __restrict__ dst, int n)
{
  int i = (blockIdx.x * 256 + threadIdx.x) * 4;
  if (i < n) {
    float4 v = *(const float4*)(src + i);
    dst[i + 0] = __float2bfloat16(v.x);
    dst[i + 1] = __float2bfloat16(v.y);
    dst[i + 2] = __float2bfloat16(v.z);
    dst[i + 3] = __float2bfloat16(v.w);
  }
}

// interleave gate/trans weights by 16-row chunks: stacked row s -> q=s>>5, r=s&31
__global__ void build_gt_kernel(const float* __restrict__ gw, const float* __restrict__ tw,
                                const float* __restrict__ gb, const float* __restrict__ tb,
                                __hip_bfloat16* __restrict__ W, float* __restrict__ bias)
{
  int idx = blockIdx.x * 256 + threadIdx.x;  // 0..2097151
  int s = idx >> 11, k = idx & 2047;
  int q = s >> 5, r = s & 31;
  float v = (r < 16) ? gw[(size_t)(q * 16 + r) * 2048 + k]
                     : tw[(size_t)(q * 16 + r - 16) * 2048 + k];
  W[idx] = __float2bfloat16(v);
  if (k == 0) bias[s] = (r < 16) ? gb[q * 16 + r] : tb[q * 16 + r - 16];
}

__global__ __launch_bounds__(64)
void ln_kernel(const float* __restrict__ H, const float* __restrict__ U,
               const float* __restrict__ g, const float* __restrict__ bta,
               float* __restrict__ out)
{
  const int row = blockIdx.x, l = threadIdx.x;
  const size_t hb = (size_t)row * 512;
  float x[8];
  float sum = 0.f;
#pragma unroll
  for (int u = 0; u < 8; ++u) {
    int d = u * 64 + l;
    float val = H[hb + d] + U[hb + d];
    x[u] = val; sum += val;
  }
#pragma unroll
  for (int m = 32; m; m >>= 1) sum += __shfl_xor(sum, m);
  float mean = sum * (1.f / 512.f);
  float vs = 0.f;
#pragma unroll
  for (int u = 0; u < 8; ++u) { float d0 = x[u] - mean; vs += d0 * d0; }
#pragma unroll
  for (int m = 32; m; m >>= 1) vs += __shfl_xor(vs, m);
  float rstd = rsqrtf(vs * (1.f / 512.f) + 1e-5f);
#pragma unroll
  for (int u = 0; u < 8; ++u) {
    int d = u * 64 + l;
    out[hb + d] = (x[u] - mean) * rstd * g[d] + bta[d];
  }
}

extern "C" void kernel_launch(void* const* d_in, const int* in_sizes, int n_in,
                              void* d_out, int out_size, void* d_ws, size_t ws_size,
                              hipStream_t stream)
{
  (void)in_sizes; (void)n_in; (void)out_size; (void)ws_size;
  const float* H      = (const float*)d_in[0];
  const int*  pred    = (const int*)d_in[1];
  const int*  maskp   = (const int*)d_in[2];
  const float* hin_w  = (const float*)d_in[3];
  const float* hin_b  = (const float*)d_in[4];
  const float* hout_w = (const float*)d_in[5];
  const float* hout_b = (const float*)d_in[6];
  const float* sin_w  = (const float*)d_in[7];
  const float* sin_b  = (const float*)d_in[8];
  const float* sout_w = (const float*)d_in[9];
  const float* sout_b = (const float*)d_in[10];
  const float* ch_w   = (const float*)d_in[11];
  const float* ch_b   = (const float*)d_in[12];
  const float* g_w    = (const float*)d_in[13];
  const float* g_b    = (const float*)d_in[14];
  const float* t_w    = (const float*)d_in[15];
  const float* t_b    = (const float*)d_in[16];
  const float* lng    = (const float*)d_in[17];
  const float* lnb    = (const float*)d_in[18];

  char* ws = (char*)d_ws;
  __hip_bfloat16* Wqkv = (__hip_bfloat16*)(ws + 0);           // 3072x512
  __hip_bfloat16* Who  = (__hip_bfloat16*)(ws + 3145728);     // 512x512
  __hip_bfloat16* Wso  = (__hip_bfloat16*)(ws + 3670016);     // 512x512
  __hip_bfloat16* Wch  = (__hip_bfloat16*)(ws + 4194304);     // 512x1024
  __hip_bfloat16* Wgt  = (__hip_bfloat16*)(ws + 5242880);     // 1024x2048 interleaved
  float* bias_qkv      = (float*)(ws + 9437184);              // 3072
  float* bias_gt       = (float*)(ws + 9449472);              // 1024
  __hip_bfloat16* Hbf  = (__hip_bfloat16*)(ws + 9453568);     // 16384x512
  __hip_bfloat16* QKV  = (__hip_bfloat16*)(ws + 26230784);    // 16384x3072
  __hip_bfloat16* Xc   = QKV;                                 // 16384x1024 (after attn)
  __hip_bfloat16* comb = (__hip_bfloat16*)(ws + 59785216);    // 16384x2048 (after attn)
  __hip_bfloat16* Ohead= (__hip_bfloat16*)(ws + 126894080);   // 16384x512
  __hip_bfloat16* Osib = (__hip_bfloat16*)(ws + 143671296);   // 16384x512
  float* U             = (float*)(ws + 126894080);            // 16384x512 (after oprojs)
  float* flags         = (float*)(ws + 160448512);            // 16384

  // weight / activation conversions
  conv_kernel<<<768, 256, 0, stream>>>(hin_w, Wqkv, 786432);
  conv_kernel<<<768, 256, 0, stream>>>(sin_w, Wqkv + 786432, 786432);
  conv_kernel<<<256, 256, 0, stream>>>(hout_w, Who, 262144);
  conv_kernel<<<256, 256, 0, stream>>>(sout_w, Wso, 262144);
  conv_kernel<<<512, 256, 0, stream>>>(ch_w, Wch, 524288);
  build_gt_kernel<<<8192, 256, 0, stream>>>(g_w, t_w, g_b, t_b, Wgt, bias_gt);
  conv_kernel<<<8192, 256, 0, stream>>>(H, Hbf, 8388608);
  hipMemcpyAsync(bias_qkv, hin_b, 1536 * 4, hipMemcpyDeviceToDevice, stream);
  hipMemcpyAsync(bias_qkv + 1536, sin_b, 1536 * 4, hipMemcpyDeviceToDevice, stream);

  // fused QKV projection for both MHAs: [16384,512] x [3072,512]^T
  gemm_kernel<0, true><<<dim3(24, 128), 256, 0, stream>>>(
      Hbf, 512, Wqkv, 512, bias_qkv, (const float*)nullptr, (void*)QKV, 3072, 512);

  // attention
  attn_kernel<false><<<1024, 256, 0, stream>>>(QKV, pred, maskp, Ohead, flags, 0);
  attn_kernel<true><<<1024, 256, 0, stream>>>(QKV, pred, maskp, Osib, flags, 1536);

  // build Xc = [Hbf | child_avg] and combined slice0 (QKV region now dead)
  pack_kernel<<<4096, 256, 0, stream>>>(Hbf, Xc, comb);
  child_kernel<<<dim3(8, 128), 256, 0, stream>>>(H, pred, maskp, Xc);

  // out-projections into combined slices
  gemm_kernel<0, true><<<dim3(4, 128), 256, 0, stream>>>(
      Ohead, 512, Who, 512, hout_b, (const float*)nullptr, (void*)(comb + 512), 2048, 512);
  gemm_kernel<0, true><<<dim3(4, 128), 256, 0, stream>>>(
      Osib, 512, Wso, 512, sout_b, flags, (void*)(comb + 1536), 2048, 512);

  // child message GEMM (gelu epilogue)
  gemm_kernel<1, true><<<dim3(4, 128), 256, 0, stream>>>(
      Xc, 1024, Wch, 1024, ch_b, (const float*)nullptr, (void*)(comb + 1024), 2048, 1024);

  // fused gate/trans GEMM -> U = sigmoid(g)*gelu(t)
  gemm_kernel<2, false><<<dim3(8, 128), 256, 0, stream>>>(
      comb, 2048, Wgt, 2048, bias_gt, (const float*)nullptr, (void*)U, 512, 2048);

  // residual + layernorm -> d_out
  ln_kernel<<<16384, 64, 0, stream>>>(H, U, lng, lnb, (float*)d_out);
}

// Round 2
// 509.192 us; speedup vs baseline: 1.1330x; 1.1330x over previous
//
#include <hip/hip_runtime.h>
#include <hip/hip_bf16.h>

typedef __bf16 bf16x8 __attribute__((ext_vector_type(8)));
typedef float f32x4 __attribute__((ext_vector_type(4)));

__device__ __forceinline__ void gload16(const void* g, void* l) {
  __builtin_amdgcn_global_load_lds(
      (const __attribute__((address_space(1))) unsigned int*)g,
      (__attribute__((address_space(3))) unsigned int*)l, 16, 0, 0);
}

__device__ __forceinline__ float gelu_f(float x) {
  return 0.5f * x * (1.f + erff(x * 0.70710678118654752f));
}
__device__ __forceinline__ float sigmoid_f(float x) {
  return 1.f / (1.f + __expf(-x));
}

// ---------------------------------------------------------------------------
// bf16 GEMM: C[m,n] = sum_k A(k)[m,k]*B[n,k] (+bias[n]) with epilogues.
// A is split into up to 3 k-segments: [0,ks1) -> A0, [ks1,ks2) -> A1, [ks2,K) -> A2.
// Tile 128x128, BK=32, 4 waves. LDS slot-swizzled (conflict-free ds_read_b128),
// applied via pre-swizzled global source (global_load_lds dest stays linear).
// EPI: 0 = plain, 1 = gelu, 2 = gate fusion (+ flag rank-1 term).
// ---------------------------------------------------------------------------
template<int EPI, bool OBF16>
__global__ __launch_bounds__(256)
void gemm_kernel(const __hip_bfloat16* __restrict__ A0, int lda0,
                 const __hip_bfloat16* __restrict__ A1, int lda1,
                 const __hip_bfloat16* __restrict__ A2, int lda2,
                 int ks1, int ks2,
                 const __hip_bfloat16* __restrict__ B, int ldb,
                 const float* __restrict__ bias,
                 const float* __restrict__ fvec,
                 const float* __restrict__ flags,
                 void* __restrict__ C, int ldc, int K)
{
  __shared__ __align__(16) __hip_bfloat16 As[128 * 32];
  __shared__ __align__(16) __hip_bfloat16 Bs[128 * 32];
  const int t = threadIdx.x;
  const int l = t & 63, w = t >> 6;
  // bijective XCD-aware block swizzle (m204)
  const int gx = gridDim.x;
  int bid = blockIdx.y * gx + blockIdx.x;
  {
    const int nwg = gx * gridDim.y;
    const int xcd = bid & 7, rk = bid >> 3, q = nwg >> 3, r = nwg & 7;
    bid = (xcd < r ? xcd * (q + 1) : r * (q + 1) + (xcd - r) * q) + rk;
  }
  const int m0 = (bid / gx) * 128, n0 = (bid % gx) * 128;
  const int wm = (w >> 1) * 64, wn = (w & 1) * 64;
  const int l15 = l & 15, lg = l >> 4;

  // staging: thread t loads row (t>>2), swizzled k-chunk ((t&3)^((t>>3)&3)).
  const int r0 = t >> 2;
  const int kk0 = ((t & 3) ^ ((t >> 3) & 3)) * 8;
  char* lA = (char*)As + t * 16;
  char* lB = (char*)Bs + t * 16;
  const size_t boff1 = (size_t)(n0 + r0) * ldb + kk0;
  const size_t boff2 = (size_t)(n0 + r0 + 64) * ldb + kk0;

  // fragment LDS read offsets (loop invariant): chunk lg of row ra lives at
  // slot lg ^ ((ra>>1)&3)
  int aoffR[4], boffR[4];
#pragma unroll
  for (int i = 0; i < 4; ++i) {
    const int ra = wm + i * 16 + l15;
    aoffR[i] = ra * 32 + ((lg ^ ((ra >> 1) & 3)) * 8);
    const int rb = wn + i * 16 + l15;
    boffR[i] = rb * 32 + ((lg ^ ((rb >> 1) & 3)) * 8);
  }
  f32x4 acc[4][4] = {};

#pragma unroll 1
  for (int seg = 0; seg < 3; ++seg) {
    const __hip_bfloat16* Ap;
    int ldA, kb, ke;
    if (seg == 0)      { Ap = A0; ldA = lda0; kb = 0;   ke = ks1; }
    else if (seg == 1) { Ap = A1; ldA = lda1; kb = ks1; ke = ks2; }
    else               { Ap = A2; ldA = lda2; kb = ks2; ke = K;   }
    if (kb >= ke) continue;
    const size_t aoff1 = (size_t)(m0 + r0) * ldA + kk0;
    const size_t aoff2 = (size_t)(m0 + r0 + 64) * ldA + kk0;
    for (int k0 = kb; k0 < ke; k0 += 32) {
      const int kr = k0 - kb;
      gload16(Ap + aoff1 + kr, lA);
      gload16(Ap + aoff2 + kr, lA + 4096);
      gload16(B + boff1 + k0, lB);
      gload16(B + boff2 + k0, lB + 4096);
      __syncthreads();
      bf16x8 af[4], bfr[4];
#pragma unroll
      for (int i = 0; i < 4; ++i) {
        af[i]  = *(const bf16x8*)((const __hip_bfloat16*)As + aoffR[i]);
        bfr[i] = *(const bf16x8*)((const __hip_bfloat16*)Bs + boffR[i]);
      }
#pragma unroll
      for (int mi = 0; mi < 4; ++mi)
#pragma unroll
        for (int ni = 0; ni < 4; ++ni)
          acc[mi][ni] = __builtin_amdgcn_mfma_f32_16x16x32_bf16(af[mi], bfr[ni], acc[mi][ni], 0, 0, 0);
      __syncthreads();
    }
  }

  if (EPI == 2) {
#pragma unroll
    for (int mi = 0; mi < 4; ++mi) {
#pragma unroll
      for (int nh = 0; nh < 2; ++nh) {
        const int ni = nh * 2;
        const int sc = n0 + wn + ni * 16;
        const float bg = bias[sc + l15], bt = bias[sc + 16 + l15];
        const float fg = fvec[sc + l15], ft = fvec[sc + 16 + l15];
        const int ocol = (sc >> 5) * 16 + l15;
#pragma unroll
        for (int j = 0; j < 4; ++j) {
          const int row = m0 + wm + mi * 16 + lg * 4 + j;
          const float flg = flags[row];
          float g  = acc[mi][ni][j]     + bg + flg * fg;
          float tv = acc[mi][ni + 1][j] + bt + flg * ft;
          ((float*)C)[(size_t)row * ldc + ocol] = sigmoid_f(g) * gelu_f(tv);
        }
      }
    }
    return;
  }
#pragma unroll
  for (int mi = 0; mi < 4; ++mi)
#pragma unroll
    for (int ni = 0; ni < 4; ++ni) {
      const int col = n0 + wn + ni * 16 + l15;
      const float bc = bias ? bias[col] : 0.f;
#pragma unroll
      for (int j = 0; j < 4; ++j) {
        const int row = m0 + wm + mi * 16 + lg * 4 + j;
        float v = acc[mi][ni][j] + bc;
        if (EPI == 1) v = gelu_f(v);
        if (OBF16) ((__hip_bfloat16*)C)[(size_t)row * ldc + col] = __float2bfloat16(v);
        else       ((float*)C)[(size_t)row * ldc + col] = v;
      }
    }
}

// ---------------------------------------------------------------------------
// Attention, one block per (b, head). Full 128x128 score tile.
// LDS tiles slot-swizzled: Q/K rows (64 el) slot' = slot ^ (row&7);
// V^T / P rows (128 el) slot' = slot ^ (row&7) over 16 slots.
// Writes O (bf16) into Oout with leading dim ldo.
// ---------------------------------------------------------------------------
template<bool SIB>
__global__ __launch_bounds__(256)
void attn_kernel(const __hip_bfloat16* __restrict__ QKV,
                 const int* __restrict__ pred_heads,
                 const int* __restrict__ mask,
                 __hip_bfloat16* __restrict__ Oout, int ldo,
                 float* __restrict__ flags,
                 int qofs)
{
  __shared__ __align__(16) __hip_bfloat16 smem[128 * 128];  // Q|K, later P
  __shared__ __align__(16) __hip_bfloat16 Vt[64 * 128];     // V transposed
  __shared__ int hs[128];
  __shared__ int mk[128];
  const int b = blockIdx.x >> 3, h = blockIdx.x & 7;
  const int t = threadIdx.x, l = t & 63, w = t >> 6;
  const int l15 = l & 15, lg = l >> 4;
  __hip_bfloat16* Qs = smem;
  __hip_bfloat16* Ks = smem + 128 * 64;

  if (t < 128) {
    int hh = pred_heads[b * 128 + t];
    hh = hh < 0 ? 0 : (hh > 127 ? 127 : hh);
    hs[t] = hh;
    mk[t] = mask[b * 128 + t];
  }
  __syncthreads();
  const size_t tb = (size_t)b * 128 * 3072;
  const int co = qofs + h * 64;
#pragma unroll
  for (int it = 0; it < 4; ++it) {
    const int idx = it * 256 + t;
    const int row = idx >> 3;
    const int c8 = (idx & 7) * 8;
    const int sl = ((c8 >> 3) ^ (row & 7)) * 8;
    *(uint4*)(Qs + row * 64 + sl) = *(const uint4*)(QKV + tb + (size_t)row * 3072 + co + c8);
    const int krow = SIB ? row : hs[row];
    *(uint4*)(Ks + row * 64 + sl) = *(const uint4*)(QKV + tb + (size_t)krow * 3072 + co + 512 + c8);
    uint4 vv = *(const uint4*)(QKV + tb + (size_t)krow * 3072 + co + 1024 + c8);
    const __hip_bfloat16* vp = (const __hip_bfloat16*)&vv;
#pragma unroll
    for (int u = 0; u < 8; ++u) {
      const int d = c8 + u;
      Vt[d * 128 + (((row >> 3) ^ (d & 7)) * 8) + (row & 7)] = vp[u];
    }
  }
  __syncthreads();

  const int r0 = w * 32;
  f32x4 s[2][8] = {};
  const int x7 = l15 & 7;
#pragma unroll
  for (int ks = 0; ks < 2; ++ks) {
    const int sl = ((ks * 4 + lg) ^ x7) * 8;
    bf16x8 qa0 = *(const bf16x8*)(Qs + (r0 + l15) * 64 + sl);
    bf16x8 qa1 = *(const bf16x8*)(Qs + (r0 + 16 + l15) * 64 + sl);
#pragma unroll
    for (int nj = 0; nj < 8; ++nj) {
      bf16x8 kb = *(const bf16x8*)(Ks + (nj * 16 + l15) * 64 + sl);
      s[0][nj] = __builtin_amdgcn_mfma_f32_16x16x32_bf16(qa0, kb, s[0][nj], 0, 0, 0);
      s[1][nj] = __builtin_amdgcn_mfma_f32_16x16x32_bf16(qa1, kb, s[1][nj], 0, 0, 0);
    }
  }
  const float scale = 0.125f;   // 1/sqrt(64)
  float inv_sum[2][4];
#pragma unroll
  for (int mi = 0; mi < 2; ++mi) {
#pragma unroll
    for (int j = 0; j < 4; ++j) {
      const int row = r0 + mi * 16 + lg * 4 + j;
      float mx = -1e30f;
#pragma unroll
      for (int nj = 0; nj < 8; ++nj) {
        float v = s[mi][nj][j] * scale;
        bool ok = true;
        if (SIB) {
          int c = nj * 16 + l15;
          ok = (hs[row] == hs[c]) && (row != c) && mk[row] && mk[c];
        }
        mx = fmaxf(mx, ok ? v : -1e30f);
      }
#pragma unroll
      for (int m = 1; m < 16; m <<= 1) mx = fmaxf(mx, __shfl_xor(mx, m));
      float sum = 0.f;
#pragma unroll
      for (int nj = 0; nj < 8; ++nj) {
        float v = s[mi][nj][j] * scale;
        bool ok = true;
        if (SIB) {
          int c = nj * 16 + l15;
          ok = (hs[row] == hs[c]) && (row != c) && mk[row] && mk[c];
        }
        float p = ok ? __expf(v - mx) : 0.f;
        s[mi][nj][j] = p;
        sum += p;
      }
#pragma unroll
      for (int m = 1; m < 16; m <<= 1) sum += __shfl_xor(sum, m);
      inv_sum[mi][j] = sum > 0.f ? 1.f / sum : 0.f;
    }
  }
  __syncthreads();  // all waves done reading Qs/Ks
#pragma unroll
  for (int mi = 0; mi < 2; ++mi)
#pragma unroll
    for (int nj = 0; nj < 8; ++nj)
#pragma unroll
      for (int j = 0; j < 4; ++j) {
        const int rr = r0 + mi * 16 + lg * 4 + j;
        const int cc = nj * 16 + l15;
        smem[rr * 128 + (((cc >> 3) ^ (rr & 7)) * 8) + (cc & 7)] = __float2bfloat16(s[mi][nj][j]);
      }
  __syncthreads();

  f32x4 o[2][4] = {};
#pragma unroll
  for (int js = 0; js < 4; ++js) {
    const int slot = js * 4 + lg;
    const int slp = (slot ^ x7) * 8;
    bf16x8 pa0 = *(const bf16x8*)(smem + (r0 + l15) * 128 + slp);
    bf16x8 pa1 = *(const bf16x8*)(smem + (r0 + 16 + l15) * 128 + slp);
#pragma unroll
    for (int dj = 0; dj < 4; ++dj) {
      bf16x8 vb = *(const bf16x8*)(Vt + (dj * 16 + l15) * 128 + slp);
      o[0][dj] = __builtin_amdgcn_mfma_f32_16x16x32_bf16(pa0, vb, o[0][dj], 0, 0, 0);
      o[1][dj] = __builtin_amdgcn_mfma_f32_16x16x32_bf16(pa1, vb, o[1][dj], 0, 0, 0);
    }
  }
  const int hb = h * 64;
#pragma unroll
  for (int mi = 0; mi < 2; ++mi)
#pragma unroll
    for (int dj = 0; dj < 4; ++dj)
#pragma unroll
      for (int j = 0; j < 4; ++j) {
        const int row = r0 + mi * 16 + lg * 4 + j;
        const int dc = dj * 16 + l15;
        const float val = o[mi][dj][j] * inv_sum[mi][j];
        Oout[(size_t)(b * 128 + row) * ldo + hb + dc] = __float2bfloat16(val);
      }
  if (SIB && h == 0 && l15 == 0) {
#pragma unroll
    for (int mi = 0; mi < 2; ++mi)
#pragma unroll
      for (int j = 0; j < 4; ++j) {
        const int row = r0 + mi * 16 + lg * 4 + j;
        flags[b * 128 + row] = inv_sum[mi][j] > 0.f ? 1.f : 0.f;
      }
  }
}

// ---------------------------------------------------------------------------
// Child aggregation -> Cavg (bf16, ld 512)
// ---------------------------------------------------------------------------
__global__ __launch_bounds__(256)
void child_kernel(const float* __restrict__ H,
                  const int* __restrict__ pred_heads,
                  const int* __restrict__ mask,
                  __hip_bfloat16* __restrict__ Cavg)
{
  __shared__ float sum[128 * 64];
  __shared__ int cnt[128];
  __shared__ int hsl[128];
  __shared__ int vld[128];
  const int t = threadIdx.x;
  const int b = blockIdx.y, ch = blockIdx.x;  // ch in 0..7
#pragma unroll
  for (int u = 0; u < 32; ++u) sum[u * 256 + t] = 0.f;
  if (t < 128) {
    int hh = pred_heads[b * 128 + t];
    hh = hh < 0 ? 0 : (hh > 127 ? 127 : hh);
    hsl[t] = hh;
    vld[t] = (mask[b * 128 + t] != 0) && (t >= 1);
    cnt[t] = 0;
  }
  __syncthreads();
  if (t < 128 && vld[t]) atomicAdd(&cnt[hsl[t]], 1);
  __syncthreads();
  const int c = t & 63;
  const int isub = t >> 6;
  for (int ii = 0; ii < 32; ++ii) {
    int i = ii * 4 + isub;
    if (vld[i]) atomicAdd(&sum[hsl[i] * 64 + c], H[((size_t)b * 128 + i) * 512 + ch * 64 + c]);
  }
  __syncthreads();
#pragma unroll
  for (int u = 0; u < 32; ++u) {
    int idx = u * 256 + t;
    int p = idx >> 6, cc = idx & 63;
    float avg = sum[idx] / fmaxf((float)cnt[p], 1.f);
    Cavg[((size_t)b * 128 + p) * 512 + ch * 64 + cc] = __float2bfloat16(avg);
  }
}

// merged fp32 -> bf16 conversions (4 segments, boundaries block-aligned)
__global__ void conv_all_kernel(const float* __restrict__ s0, const float* __restrict__ s1,
                                const float* __restrict__ s2, const float* __restrict__ s3,
                                __hip_bfloat16* __restrict__ d0, __hip_bfloat16* __restrict__ d1,
                                __hip_bfloat16* __restrict__ d2, __hip_bfloat16* __restrict__ d3)
{
  int gid = blockIdx.x * 256 + threadIdx.x;
  const float* s; __hip_bfloat16* d; int i;
  if      (gid <  196608) { s = s0; d = d0; i = gid; }
  else if (gid <  393216) { s = s1; d = d1; i = gid - 196608; }
  else if (gid <  524288) { s = s2; d = d2; i = gid - 393216; }
  else                    { s = s3; d = d3; i = gid - 524288; }
  i *= 4;
  float4 v = *(const float4*)(s + i);
  union { __hip_bfloat16 h[4]; uint2 u; } p;
  p.h[0] = __float2bfloat16(v.x); p.h[1] = __float2bfloat16(v.y);
  p.h[2] = __float2bfloat16(v.z); p.h[3] = __float2bfloat16(v.w);
  *(uint2*)(d + i) = p.u;
}

// transposed fp32 -> bf16 for the two 512x512 out-proj weights
__global__ void convT_kernel(const float* __restrict__ a, const float* __restrict__ b,
                             __hip_bfloat16* __restrict__ ta, __hip_bfloat16* __restrict__ tb)
{
  int idx = blockIdx.x * 256 + threadIdx.x;  // 0..524287
  const float* s = a; __hip_bfloat16* d = ta;
  if (idx >= 262144) { s = b; d = tb; idx -= 262144; }
  int i = idx >> 9, j = idx & 511;
  d[i * 512 + j] = __float2bfloat16(s[(size_t)j * 512 + i]);
}

// interleave gate/trans weights; route slices:
// c<512 -> Wf[:,0:512] (H), 512<=c<1024 -> Whin (head), 1024<=c<1536 -> Wf[:,512:1024] (child),
// c>=1536 -> Wsin (sib). bias_gt from gb/tb.
__global__ void build_gt_kernel(const float* __restrict__ gw, const float* __restrict__ tw,
                                const float* __restrict__ gb, const float* __restrict__ tb,
                                __hip_bfloat16* __restrict__ Wf, __hip_bfloat16* __restrict__ Whin,
                                __hip_bfloat16* __restrict__ Wsin, float* __restrict__ bias)
{
  int idx = blockIdx.x * 256 + threadIdx.x;  // 0..2097151
  int s = idx >> 11, c = idx & 2047;
  int q = s >> 5, r = s & 31;
  float v = (r < 16) ? gw[(size_t)(q * 16 + r) * 2048 + c]
                     : tw[(size_t)(q * 16 + r - 16) * 2048 + c];
  __hip_bfloat16 hv = __float2bfloat16(v);
  if      (c <  512) Wf[(size_t)s * 2048 + c] = hv;
  else if (c < 1024) Whin[(size_t)s * 512 + (c - 512)] = hv;
  else if (c < 1536) Wf[(size_t)s * 2048 + (c - 512)] = hv;
  else               Wsin[(size_t)s * 512 + (c - 1536)] = hv;
  if (c == 0) bias[s] = (r < 16) ? gb[q * 16 + r] : tb[q * 16 + r - 16];
}

// bias folds: bias_gt[s] += Whin[s,:].hout_b ; fvec[s] = Wsin[s,:].sout_b
__global__ __launch_bounds__(256)
void foldbias_kernel(const __hip_bfloat16* __restrict__ Whin, const __hip_bfloat16* __restrict__ Wsin,
                     const float* __restrict__ hob, const float* __restrict__ sob,
                     float* __restrict__ bias_gt, float* __restrict__ fvec)
{
  const int s = blockIdx.x * 256 + threadIdx.x;  // 0..1023
  float a = 0.f, c = 0.f;
  for (int j = 0; j < 512; j += 8) {
    bf16x8 wh = *(const bf16x8*)(Whin + (size_t)s * 512 + j);
    bf16x8 wsv = *(const bf16x8*)(Wsin + (size_t)s * 512 + j);
#pragma unroll
    for (int u = 0; u < 8; ++u) {
      a += (float)wh[u] * hob[j + u];
      c += (float)wsv[u] * sob[j + u];
    }
  }
  bias_gt[s] += a;
  fvec[s] = c;
}

__global__ __launch_bounds__(64)
void ln_kernel(const float* __restrict__ H, const float* __restrict__ U,
               const float* __restrict__ g, const float* __restrict__ bta,
               float* __restrict__ out)
{
  const int row = blockIdx.x, l = threadIdx.x;
  const size_t hb = (size_t)row * 512;
  float x[8];
  float sum = 0.f;
#pragma unroll
  for (int u = 0; u < 8; ++u) {
    int d = u * 64 + l;
    float val = H[hb + d] + U[hb + d];
    x[u] = val; sum += val;
  }
#pragma unroll
  for (int m = 32; m; m >>= 1) sum += __shfl_xor(sum, m);
  float mean = sum * (1.f / 512.f);
  float vs = 0.f;
#pragma unroll
  for (int u = 0; u < 8; ++u) { float d0 = x[u] - mean; vs += d0 * d0; }
#pragma unroll
  for (int m = 32; m; m >>= 1) vs += __shfl_xor(vs, m);
  float rstd = rsqrtf(vs * (1.f / 512.f) + 1e-5f);
#pragma unroll
  for (int u = 0; u < 8; ++u) {
    int d = u * 64 + l;
    out[hb + d] = (x[u] - mean) * rstd * g[d] + bta[d];
  }
}

extern "C" void kernel_launch(void* const* d_in, const int* in_sizes, int n_in,
                              void* d_out, int out_size, void* d_ws, size_t ws_size,
                              hipStream_t stream)
{
  (void)in_sizes; (void)n_in; (void)out_size; (void)ws_size;
  const float* H      = (const float*)d_in[0];
  const int*  pred    = (const int*)d_in[1];
  const int*  maskp   = (const int*)d_in[2];
  const float* hin_w  = (const float*)d_in[3];
  const float* hin_b  = (const float*)d_in[4];
  const float* hout_w = (const float*)d_in[5];
  const float* hout_b = (const float*)d_in[6];
  const float* sin_w  = (const float*)d_in[7];
  const float* sin_b  = (const float*)d_in[8];
  const float* sout_w = (const float*)d_in[9];
  const float* sout_b = (const float*)d_in[10];
  const float* ch_w   = (const float*)d_in[11];
  const float* ch_b   = (const float*)d_in[12];
  const float* g_w    = (const float*)d_in[13];
  const float* g_b    = (const float*)d_in[14];
  const float* t_w    = (const float*)d_in[15];
  const float* t_b    = (const float*)d_in[16];
  const float* lng    = (const float*)d_in[17];
  const float* lnb    = (const float*)d_in[18];

  char* ws = (char*)d_ws;
  __hip_bfloat16* Wqkv  = (__hip_bfloat16*)(ws + 0);          // 3072x512
  __hip_bfloat16* Wch   = (__hip_bfloat16*)(ws + 3145728);    // 512x1024
  __hip_bfloat16* Wgt   = (__hip_bfloat16*)(ws + 4194304);    // 1024x2048 (final, interleaved)
  float* bias_qkv       = (float*)(ws + 8388608);             // 3072
  float* bias_gt        = (float*)(ws + 8400896);             // 1024
  float* fvec           = (float*)(ws + 8404992);             // 1024
  float* flags          = (float*)(ws + 8409088);             // 16384
  __hip_bfloat16* Hbf   = (__hip_bfloat16*)(ws + 8474624);    // 16384x512
  char* QKVr            = ws + 25251840;                      // 100.7 MB region
  __hip_bfloat16* QKV   = (__hip_bfloat16*)QKVr;              // 16384x3072
  // pre-QKV residents inside QKVr (dead before QKV gemm writes):
  __hip_bfloat16* Whin  = (__hip_bfloat16*)(QKVr + 0);        // 1024x512
  __hip_bfloat16* Wsin  = (__hip_bfloat16*)(QKVr + 1048576);  // 1024x512
  __hip_bfloat16* WhoT  = (__hip_bfloat16*)(QKVr + 2097152);  // 512x512
  __hip_bfloat16* WsoT  = (__hip_bfloat16*)(QKVr + 2621440);  // 512x512
  // post-attention residents inside QKVr (QKV dead by then):
  __hip_bfloat16* CHM   = (__hip_bfloat16*)(QKVr + 0);           // 16384x512 (child_msg)
  float* U              = (float*)(QKVr + 16777216);             // 16384x512 fp32
  __hip_bfloat16* Cavg  = (__hip_bfloat16*)(QKVr + 50331648);    // 16384x512
  __hip_bfloat16* CM2   = (__hip_bfloat16*)(ws + 125915136);  // 16384x1024 [Ohead|Osib]

  // conversions: hin_w, sin_w -> Wqkv; ch_w -> Wch; H -> Hbf
  conv_all_kernel<<<10240, 256, 0, stream>>>(hin_w, sin_w, ch_w, H,
                                             Wqkv, Wqkv + 786432, Wch, Hbf);
  build_gt_kernel<<<8192, 256, 0, stream>>>(g_w, t_w, g_b, t_b, Wgt, Whin, Wsin, bias_gt);
  convT_kernel<<<2048, 256, 0, stream>>>(hout_w, sout_w, WhoT, WsoT);
  foldbias_kernel<<<4, 256, 0, stream>>>(Whin, Wsin, hout_b, sout_b, bias_gt, fvec);
  hipMemcpyAsync(bias_qkv, hin_b, 1536 * 4, hipMemcpyDeviceToDevice, stream);
  hipMemcpyAsync(bias_qkv + 1536, sin_b, 1536 * 4, hipMemcpyDeviceToDevice, stream);

  // weight folds: Wgt[:,1024:1536] = Whin @ WhoT^T ; Wgt[:,1536:2048] = Wsin @ WsoT^T
  gemm_kernel<0, true><<<dim3(4, 8), 256, 0, stream>>>(
      Whin, 512, Whin, 512, Whin, 512, 512, 512, WhoT, 512,
      (const float*)nullptr, (const float*)nullptr, (const float*)nullptr,
      (void*)(Wgt + 1024), 2048, 512);
  gemm_kernel<0, true><<<dim3(4, 8), 256, 0, stream>>>(
      Wsin, 512, Wsin, 512, Wsin, 512, 512, 512, WsoT, 512,
      (const float*)nullptr, (const float*)nullptr, (const float*)nullptr,
      (void*)(Wgt + 1536), 2048, 512);

  // fused QKV projection for both MHAs (overwrites Whin/Wsin/WhoT/WsoT region)
  gemm_kernel<0, true><<<dim3(24, 128), 256, 0, stream>>>(
      Hbf, 512, Hbf, 512, Hbf, 512, 512, 512, Wqkv, 512,
      bias_qkv, (const float*)nullptr, (const float*)nullptr,
      (void*)QKV, 3072, 512);

  // attention -> CM2 slices
  attn_kernel<false><<<1024, 256, 0, stream>>>(QKV, pred, maskp, CM2, 1024, flags, 0);
  attn_kernel<true><<<1024, 256, 0, stream>>>(QKV, pred, maskp, CM2 + 512, 1024, flags, 1536);

  // child aggregation + child message GEMM (QKV dead now)
  child_kernel<<<dim3(8, 128), 256, 0, stream>>>(H, pred, maskp, Cavg);
  gemm_kernel<1, true><<<dim3(4, 128), 256, 0, stream>>>(
      Hbf, 512, Cavg, 512, Cavg, 512, 512, 1024, Wch, 1024,
      ch_b, (const float*)nullptr, (const float*)nullptr,
      (void*)CHM, 512, 1024);

  // fused gate/trans GEMM over virtual comb = [Hbf | CHM | CM2]
  gemm_kernel<2, false><<<dim3(8, 128), 256, 0, stream>>>(
      Hbf, 512, CHM, 512, CM2, 1024, 512, 1024, Wgt, 2048,
      bias_gt, fvec, flags, (void*)U, 512, 2048);

  // residual + layernorm -> d_out
  ln_kernel<<<16384, 64, 0, stream>>>(H, U, lng, lnb, (float*)d_out);
}

// Round 5
// 488.514 us; speedup vs baseline: 1.1810x; 1.0423x over previous
//
#include <hip/hip_runtime.h>
#include <hip/hip_bf16.h>

typedef __bf16 bf16x8 __attribute__((ext_vector_type(8)));
typedef float f32x4 __attribute__((ext_vector_type(4)));

__device__ __forceinline__ void gload16(const void* g, void* l) {
  __builtin_amdgcn_global_load_lds(
      (const __attribute__((address_space(1))) unsigned int*)g,
      (__attribute__((address_space(3))) unsigned int*)l, 16, 0, 0);
}

__device__ __forceinline__ float gelu_f(float x) {
  return 0.5f * x * (1.f + erff(x * 0.70710678118654752f));
}
__device__ __forceinline__ float sigmoid_f(float x) {
  return 1.f / (1.f + __expf(-x));
}

// ---------------------------------------------------------------------------
// 8-wave 256x256 deep-pipelined GEMM (T3+T4+T5): BK=32, 4 LDS buffers
// (128 KiB dynamic), prefetch depth 3, counted vmcnt(8) (never 0 in loop),
// 1 raw barrier per K-tile, setprio around MFMA clusters.
// A split into up to 3 k-segments. EPI: 0 = bias+bf16, 2 = gate fusion fp32.
// ---------------------------------------------------------------------------
template<int EPI>
__global__ __launch_bounds__(512, 2)
void gemm8_kernel(const __hip_bfloat16* __restrict__ A0, int lda0,
                  const __hip_bfloat16* __restrict__ A1, int lda1,
                  const __hip_bfloat16* __restrict__ A2, int lda2,
                  int ks1, int ks2,
                  const __hip_bfloat16* __restrict__ B, int ldb,
                  const float* __restrict__ bias,
                  const float* __restrict__ fvec,
                  const float* __restrict__ flags,
                  void* __restrict__ C, int ldc, int K)
{
  extern __shared__ __align__(16) char lds[];
  const int t = threadIdx.x;
  const int l = t & 63;
  const int w = t >> 6;
  const int l15 = l & 15, lg = (l >> 4) & 3;
  // n-outer logical order + bijective XCD swizzle (m204)
  const int orig = blockIdx.y * gridDim.x + blockIdx.x;
  const int nwg = gridDim.x * gridDim.y;
  const int gy = gridDim.y;
  const int xcd = orig & 7, rk = orig >> 3, q = nwg >> 3, r = nwg & 7;
  const int bid = (xcd < r ? xcd * (q + 1) : r * (q + 1) + (xcd - r) * q) + rk;
  const int m0 = (bid % gy) * 256;
  const int n0 = (bid / gy) * 256;

  // staging: thread t handles 16B chunk; row = t>>2, slot = t&3,
  // global k-chunk = slot ^ ((row>>1)&3)  (same involution as read side)
  const int srow = t >> 2;
  const int kc8 = ((t & 3) ^ ((t >> 3) & 3)) * 8;
  const int mbase = (w >> 2) * 128;
  const int nbase = (w & 3) * 64;
  const int swz = (l15 >> 1) & 3;
  const int kslot = (lg ^ swz) * 8;
  int aoff[8], boff[4];
#pragma unroll
  for (int mf = 0; mf < 8; ++mf) aoff[mf] = (mbase + mf * 16 + l15) * 32 + kslot;
#pragma unroll
  for (int nf = 0; nf < 4; ++nf) boff[nf] = (nbase + nf * 16 + l15) * 32 + kslot;

  auto segA = [&](int k0, const __hip_bfloat16*& Ap, int& ldA, int& krel) {
    if (k0 >= ks2)      { Ap = A2; ldA = lda2; krel = k0 - ks2; }
    else if (k0 >= ks1) { Ap = A1; ldA = lda1; krel = k0 - ks1; }
    else                { Ap = A0; ldA = lda0; krel = k0; }
  };
  auto stageA = [&](int buf, const __hip_bfloat16* Ap, int ldA, int krel) {
    char* base = lds + buf * 32768 + t * 16;
    gload16(Ap + (size_t)(m0 + srow) * ldA + krel + kc8, base);
    gload16(Ap + (size_t)(m0 + 128 + srow) * ldA + krel + kc8, base + 8192);
  };
  auto stageB = [&](int buf, int k0) {
    char* base = lds + buf * 32768 + 16384 + t * 16;
    gload16(B + (size_t)(n0 + srow) * ldb + k0 + kc8, base);
    gload16(B + (size_t)(n0 + 128 + srow) * ldb + k0 + kc8, base + 8192);
  };

  f32x4 acc[8][4] = {};
  const int NT = K >> 5;

  // prologue: stage tiles 0,1,2 (12 loads/thread); wait tile0 (drain to 8)
#pragma unroll 1
  for (int pt = 0; pt < 3; ++pt) {
    const __hip_bfloat16* Ap; int ldA, krel;
    segA(pt * 32, Ap, ldA, krel);
    stageA(pt, Ap, ldA, krel);
    stageB(pt, pt * 32);
  }
  asm volatile("s_waitcnt vmcnt(8)" ::: "memory");
  __builtin_amdgcn_s_barrier();
  __builtin_amdgcn_sched_barrier(0);

#pragma unroll 1
  for (int tt = 0; tt < NT; ++tt) {
    const int buf = tt & 3;
    const __hip_bfloat16* As = (const __hip_bfloat16*)(lds + buf * 32768);
    const __hip_bfloat16* Bs = (const __hip_bfloat16*)(lds + buf * 32768 + 16384);
    const int pf = tt + 3;
    const bool do_pf = pf < NT;
    const int pbuf = pf & 3;
    const __hip_bfloat16* Ap = A0; int ldA = lda0, krel = 0;
    if (do_pf) segA(pf * 32, Ap, ldA, krel);

    bf16x8 bv[4], av[4];
    // phase A: frags for m-frags 0-3 (all 4 n-frags), stage A-halves of t+3
#pragma unroll
    for (int nf = 0; nf < 4; ++nf) bv[nf] = *(const bf16x8*)(Bs + boff[nf]);
#pragma unroll
    for (int mf = 0; mf < 4; ++mf) av[mf] = *(const bf16x8*)(As + aoff[mf]);
    if (do_pf) stageA(pbuf, Ap, ldA, krel);
    __builtin_amdgcn_s_setprio(1);
#pragma unroll
    for (int mf = 0; mf < 4; ++mf)
#pragma unroll
      for (int nf = 0; nf < 4; ++nf)
        acc[mf][nf] = __builtin_amdgcn_mfma_f32_16x16x32_bf16(av[mf], bv[nf], acc[mf][nf], 0, 0, 0);
    __builtin_amdgcn_s_setprio(0);

    // phase B: m-frags 4-7, stage B-halves of t+3
#pragma unroll
    for (int mf = 0; mf < 4; ++mf) av[mf] = *(const bf16x8*)(As + aoff[mf + 4]);
    if (do_pf) stageB(pbuf, pf * 32);
    __builtin_amdgcn_s_setprio(1);
#pragma unroll
    for (int mf = 0; mf < 4; ++mf)
#pragma unroll
      for (int nf = 0; nf < 4; ++nf)
        acc[mf + 4][nf] = __builtin_amdgcn_mfma_f32_16x16x32_bf16(av[mf], bv[nf], acc[mf + 4][nf], 0, 0, 0);
    __builtin_amdgcn_s_setprio(0);

    // K-tile boundary: counted drain (tile t+1 landed), one barrier
    __builtin_amdgcn_sched_barrier(0);
    if (tt + 3 < NT)      asm volatile("s_waitcnt vmcnt(8)" ::: "memory");
    else if (tt + 2 < NT) asm volatile("s_waitcnt vmcnt(4)" ::: "memory");
    else if (tt + 1 < NT) asm volatile("s_waitcnt vmcnt(0)" ::: "memory");
    if (tt + 1 < NT) {
      __builtin_amdgcn_s_barrier();
      __builtin_amdgcn_sched_barrier(0);
    }
  }

  if (EPI == 2) {
#pragma unroll
    for (int mf = 0; mf < 8; ++mf) {
#pragma unroll
      for (int nh = 0; nh < 2; ++nh) {
        const int nf = nh * 2;
        const int sc = n0 + nbase + nf * 16;
        const float bg = bias[sc + l15], bt = bias[sc + 16 + l15];
        const float fg = fvec[sc + l15], ft = fvec[sc + 16 + l15];
        const int ocol = (sc >> 5) * 16 + l15;
#pragma unroll
        for (int j = 0; j < 4; ++j) {
          const int row = m0 + mbase + mf * 16 + lg * 4 + j;
          const float flg = flags[row];
          float g  = acc[mf][nf][j]     + bg + flg * fg;
          float tv = acc[mf][nf + 1][j] + bt + flg * ft;
          ((float*)C)[(size_t)row * ldc + ocol] = sigmoid_f(g) * gelu_f(tv);
        }
      }
    }
    return;
  }
#pragma unroll
  for (int mf = 0; mf < 8; ++mf)
#pragma unroll
    for (int nf = 0; nf < 4; ++nf) {
      const int col = n0 + nbase + nf * 16 + l15;
      const float bc = bias ? bias[col] : 0.f;
#pragma unroll
      for (int j = 0; j < 4; ++j) {
        const int row = m0 + mbase + mf * 16 + lg * 4 + j;
        ((__hip_bfloat16*)C)[(size_t)row * ldc + col] =
            __float2bfloat16(acc[mf][nf][j] + bc);
      }
    }
}

// ---------------------------------------------------------------------------
// 128x128 2-phase GEMM (kept for small/odd shapes: child GEMM, weight folds)
// ---------------------------------------------------------------------------
template<int EPI, bool OBF16>
__global__ __launch_bounds__(256)
void gemm_kernel(const __hip_bfloat16* __restrict__ A0, int lda0,
                 const __hip_bfloat16* __restrict__ A1, int lda1,
                 const __hip_bfloat16* __restrict__ A2, int lda2,
                 int ks1, int ks2,
                 const __hip_bfloat16* __restrict__ B, int ldb,
                 const float* __restrict__ bias,
                 const float* __restrict__ fvec,
                 const float* __restrict__ flags,
                 void* __restrict__ C, int ldc, int K)
{
  __shared__ __align__(16) __hip_bfloat16 As[128 * 32];
  __shared__ __align__(16) __hip_bfloat16 Bs[128 * 32];
  const int t = threadIdx.x;
  const int l = t & 63, w = t >> 6;
  const int gx = gridDim.x;
  int bid = blockIdx.y * gx + blockIdx.x;
  {
    const int nwg = gx * gridDim.y;
    const int xcd = bid & 7, rk = bid >> 3, q = nwg >> 3, r = nwg & 7;
    bid = (xcd < r ? xcd * (q + 1) : r * (q + 1) + (xcd - r) * q) + rk;
  }
  const int m0 = (bid / gx) * 128, n0 = (bid % gx) * 128;
  const int wm = (w >> 1) * 64, wn = (w & 1) * 64;
  const int l15 = l & 15, lg = l >> 4;

  const int r0 = t >> 2;
  const int kk0 = ((t & 3) ^ ((t >> 3) & 3)) * 8;
  char* lA = (char*)As + t * 16;
  char* lB = (char*)Bs + t * 16;
  const size_t boff1 = (size_t)(n0 + r0) * ldb + kk0;
  const size_t boff2 = (size_t)(n0 + r0 + 64) * ldb + kk0;

  int aoffR[4], boffR[4];
#pragma unroll
  for (int i = 0; i < 4; ++i) {
    const int ra = wm + i * 16 + l15;
    aoffR[i] = ra * 32 + ((lg ^ ((ra >> 1) & 3)) * 8);
    const int rb = wn + i * 16 + l15;
    boffR[i] = rb * 32 + ((lg ^ ((rb >> 1) & 3)) * 8);
  }
  f32x4 acc[4][4] = {};

#pragma unroll 1
  for (int seg = 0; seg < 3; ++seg) {
    const __hip_bfloat16* Ap;
    int ldA, kb, ke;
    if (seg == 0)      { Ap = A0; ldA = lda0; kb = 0;   ke = ks1; }
    else if (seg == 1) { Ap = A1; ldA = lda1; kb = ks1; ke = ks2; }
    else               { Ap = A2; ldA = lda2; kb = ks2; ke = K;   }
    if (kb >= ke) continue;
    const size_t aoff1 = (size_t)(m0 + r0) * ldA + kk0;
    const size_t aoff2 = (size_t)(m0 + r0 + 64) * ldA + kk0;
    for (int k0 = kb; k0 < ke; k0 += 32) {
      const int kr = k0 - kb;
      gload16(Ap + aoff1 + kr, lA);
      gload16(Ap + aoff2 + kr, lA + 4096);
      gload16(B + boff1 + k0, lB);
      gload16(B + boff2 + k0, lB + 4096);
      __syncthreads();
      bf16x8 af[4], bfr[4];
#pragma unroll
      for (int i = 0; i < 4; ++i) {
        af[i]  = *(const bf16x8*)((const __hip_bfloat16*)As + aoffR[i]);
        bfr[i] = *(const bf16x8*)((const __hip_bfloat16*)Bs + boffR[i]);
      }
#pragma unroll
      for (int mi = 0; mi < 4; ++mi)
#pragma unroll
        for (int ni = 0; ni < 4; ++ni)
          acc[mi][ni] = __builtin_amdgcn_mfma_f32_16x16x32_bf16(af[mi], bfr[ni], acc[mi][ni], 0, 0, 0);
      __syncthreads();
    }
  }

#pragma unroll
  for (int mi = 0; mi < 4; ++mi)
#pragma unroll
    for (int ni = 0; ni < 4; ++ni) {
      const int col = n0 + wn + ni * 16 + l15;
      const float bc = bias ? bias[col] : 0.f;
#pragma unroll
      for (int j = 0; j < 4; ++j) {
        const int row = m0 + wm + mi * 16 + lg * 4 + j;
        float v = acc[mi][ni][j] + bc;
        if (EPI == 1) v = gelu_f(v);
        if (OBF16) ((__hip_bfloat16*)C)[(size_t)row * ldc + col] = __float2bfloat16(v);
        else       ((float*)C)[(size_t)row * ldc + col] = v;
      }
    }
}

// ---------------------------------------------------------------------------
// Attention, one block per (b, head). Full 128x128 score tile, slot-swizzled.
// ---------------------------------------------------------------------------
template<bool SIB>
__global__ __launch_bounds__(256)
void attn_kernel(const __hip_bfloat16* __restrict__ QKV,
                 const int* __restrict__ pred_heads,
                 const int* __restrict__ mask,
                 __hip_bfloat16* __restrict__ Oout, int ldo,
                 float* __restrict__ flags,
                 int qofs)
{
  __shared__ __align__(16) __hip_bfloat16 smem[128 * 128];  // Q|K, later P
  __shared__ __align__(16) __hip_bfloat16 Vt[64 * 128];     // V transposed
  __shared__ int hs[128];
  __shared__ int mk[128];
  const int b = blockIdx.x >> 3, h = blockIdx.x & 7;
  const int t = threadIdx.x, l = t & 63, w = t >> 6;
  const int l15 = l & 15, lg = l >> 4;
  __hip_bfloat16* Qs = smem;
  __hip_bfloat16* Ks = smem + 128 * 64;

  if (t < 128) {
    int hh = pred_heads[b * 128 + t];
    hh = hh < 0 ? 0 : (hh > 127 ? 127 : hh);
    hs[t] = hh;
    mk[t] = mask[b * 128 + t];
  }
  __syncthreads();
  const size_t tb = (size_t)b * 128 * 3072;
  const int co = qofs + h * 64;
#pragma unroll
  for (int it = 0; it < 4; ++it) {
    const int idx = it * 256 + t;
    const int row = idx >> 3;
    const int c8 = (idx & 7) * 8;
    const int sl = ((c8 >> 3) ^ (row & 7)) * 8;
    *(uint4*)(Qs + row * 64 + sl) = *(const uint4*)(QKV + tb + (size_t)row * 3072 + co + c8);
    const int krow = SIB ? row : hs[row];
    *(uint4*)(Ks + row * 64 + sl) = *(const uint4*)(QKV + tb + (size_t)krow * 3072 + co + 512 + c8);
    uint4 vv = *(const uint4*)(QKV + tb + (size_t)krow * 3072 + co + 1024 + c8);
    const __hip_bfloat16* vp = (const __hip_bfloat16*)&vv;
#pragma unroll
    for (int u = 0; u < 8; ++u) {
      const int d = c8 + u;
      Vt[d * 128 + (((row >> 3) ^ (d & 7)) * 8) + (row & 7)] = vp[u];
    }
  }
  __syncthreads();

  const int r0 = w * 32;
  f32x4 s[2][8] = {};
  const int x7 = l15 & 7;
#pragma unroll
  for (int ks = 0; ks < 2; ++ks) {
    const int sl = ((ks * 4 + lg) ^ x7) * 8;
    bf16x8 qa0 = *(const bf16x8*)(Qs + (r0 + l15) * 64 + sl);
    bf16x8 qa1 = *(const bf16x8*)(Qs + (r0 + 16 + l15) * 64 + sl);
#pragma unroll
    for (int nj = 0; nj < 8; ++nj) {
      bf16x8 kb = *(const bf16x8*)(Ks + (nj * 16 + l15) * 64 + sl);
      s[0][nj] = __builtin_amdgcn_mfma_f32_16x16x32_bf16(qa0, kb, s[0][nj], 0, 0, 0);
      s[1][nj] = __builtin_amdgcn_mfma_f32_16x16x32_bf16(qa1, kb, s[1][nj], 0, 0, 0);
    }
  }
  const float scale = 0.125f;   // 1/sqrt(64)
  float inv_sum[2][4];
#pragma unroll
  for (int mi = 0; mi < 2; ++mi) {
#pragma unroll
    for (int j = 0; j < 4; ++j) {
      const int row = r0 + mi * 16 + lg * 4 + j;
      float mx = -1e30f;
#pragma unroll
      for (int nj = 0; nj < 8; ++nj) {
        float v = s[mi][nj][j] * scale;
        bool ok = true;
        if (SIB) {
          int c = nj * 16 + l15;
          ok = (hs[row] == hs[c]) && (row != c) && mk[row] && mk[c];
        }
        mx = fmaxf(mx, ok ? v : -1e30f);
      }
#pragma unroll
      for (int m = 1; m < 16; m <<= 1) mx = fmaxf(mx, __shfl_xor(mx, m));
      float sum = 0.f;
#pragma unroll
      for (int nj = 0; nj < 8; ++nj) {
        float v = s[mi][nj][j] * scale;
        bool ok = true;
        if (SIB) {
          int c = nj * 16 + l15;
          ok = (hs[row] == hs[c]) && (row != c) && mk[row] && mk[c];
        }
        float p = ok ? __expf(v - mx) : 0.f;
        s[mi][nj][j] = p;
        sum += p;
      }
#pragma unroll
      for (int m = 1; m < 16; m <<= 1) sum += __shfl_xor(sum, m);
      inv_sum[mi][j] = sum > 0.f ? 1.f / sum : 0.f;
    }
  }
  __syncthreads();  // all waves done reading Qs/Ks
#pragma unroll
  for (int mi = 0; mi < 2; ++mi)
#pragma unroll
    for (int nj = 0; nj < 8; ++nj)
#pragma unroll
      for (int j = 0; j < 4; ++j) {
        const int rr = r0 + mi * 16 + lg * 4 + j;
        const int cc = nj * 16 + l15;
        smem[rr * 128 + (((cc >> 3) ^ (rr & 7)) * 8) + (cc & 7)] = __float2bfloat16(s[mi][nj][j]);
      }
  __syncthreads();

  f32x4 o[2][4] = {};
#pragma unroll
  for (int js = 0; js < 4; ++js) {
    const int slot = js * 4 + lg;
    const int slp = (slot ^ x7) * 8;
    bf16x8 pa0 = *(const bf16x8*)(smem + (r0 + l15) * 128 + slp);
    bf16x8 pa1 = *(const bf16x8*)(smem + (r0 + 16 + l15) * 128 + slp);
#pragma unroll
    for (int dj = 0; dj < 4; ++dj) {
      bf16x8 vb = *(const bf16x8*)(Vt + (dj * 16 + l15) * 128 + slp);
      o[0][dj] = __builtin_amdgcn_mfma_f32_16x16x32_bf16(pa0, vb, o[0][dj], 0, 0, 0);
      o[1][dj] = __builtin_amdgcn_mfma_f32_16x16x32_bf16(pa1, vb, o[1][dj], 0, 0, 0);
    }
  }
  const int hb = h * 64;
#pragma unroll
  for (int mi = 0; mi < 2; ++mi)
#pragma unroll
    for (int dj = 0; dj < 4; ++dj)
#pragma unroll
      for (int j = 0; j < 4; ++j) {
        const int row = r0 + mi * 16 + lg * 4 + j;
        const int dc = dj * 16 + l15;
        const float val = o[mi][dj][j] * inv_sum[mi][j];
        Oout[(size_t)(b * 128 + row) * ldo + hb + dc] = __float2bfloat16(val);
      }
  if (SIB && h == 0 && l15 == 0) {
#pragma unroll
    for (int mi = 0; mi < 2; ++mi)
#pragma unroll
      for (int j = 0; j < 4; ++j) {
        const int row = r0 + mi * 16 + lg * 4 + j;
        flags[b * 128 + row] = inv_sum[mi][j] > 0.f ? 1.f : 0.f;
      }
  }
}

// ---------------------------------------------------------------------------
// Child aggregation -> Cavg (bf16, ld 512)
// ---------------------------------------------------------------------------
__global__ __launch_bounds__(256)
void child_kernel(const float* __restrict__ H,
                  const int* __restrict__ pred_heads,
                  const int* __restrict__ mask,
                  __hip_bfloat16* __restrict__ Cavg)
{
  __shared__ float sum[128 * 64];
  __shared__ int cnt[128];
  __shared__ int hsl[128];
  __shared__ int vld[128];
  const int t = threadIdx.x;
  const int b = blockIdx.y, ch = blockIdx.x;  // ch in 0..7
#pragma unroll
  for (int u = 0; u < 32; ++u) sum[u * 256 + t] = 0.f;
  if (t < 128) {
    int hh = pred_heads[b * 128 + t];
    hh = hh < 0 ? 0 : (hh > 127 ? 127 : hh);
    hsl[t] = hh;
    vld[t] = (mask[b * 128 + t] != 0) && (t >= 1);
    cnt[t] = 0;
  }
  __syncthreads();
  if (t < 128 && vld[t]) atomicAdd(&cnt[hsl[t]], 1);
  __syncthreads();
  const int c = t & 63;
  const int isub = t >> 6;
  for (int ii = 0; ii < 32; ++ii) {
    int i = ii * 4 + isub;
    if (vld[i]) atomicAdd(&sum[hsl[i] * 64 + c], H[((size_t)b * 128 + i) * 512 + ch * 64 + c]);
  }
  __syncthreads();
#pragma unroll
  for (int u = 0; u < 32; ++u) {
    int idx = u * 256 + t;
    int p = idx >> 6, cc = idx & 63;
    float avg = sum[idx] / fmaxf((float)cnt[p], 1.f);
    Cavg[((size_t)b * 128 + p) * 512 + ch * 64 + cc] = __float2bfloat16(avg);
  }
}

// merged fp32 -> bf16 conversions (4 segments, boundaries block-aligned)
__global__ void conv_all_kernel(const float* __restrict__ s0, const float* __restrict__ s1,
                                const float* __restrict__ s2, const float* __restrict__ s3,
                                __hip_bfloat16* __restrict__ d0, __hip_bfloat16* __restrict__ d1,
                                __hip_bfloat16* __restrict__ d2, __hip_bfloat16* __restrict__ d3)
{
  int gid = blockIdx.x * 256 + threadIdx.x;
  const float* s; __hip_bfloat16* d; int i;
  if      (gid <  196608) { s = s0; d = d0; i = gid; }
  else if (gid <  393216) { s = s1; d = d1; i = gid - 196608; }
  else if (gid <  524288) { s = s2; d = d2; i = gid - 393216; }
  else                    { s = s3; d = d3; i = gid - 524288; }
  i *= 4;
  float4 v = *(const float4*)(s + i);
  union { __hip_bfloat16 h[4]; uint2 u; } p;
  p.h[0] = __float2bfloat16(v.x); p.h[1] = __float2bfloat16(v.y);
  p.h[2] = __float2bfloat16(v.z); p.h[3] = __float2bfloat16(v.w);
  *(uint2*)(d + i) = p.u;
}

// transposed fp32 -> bf16 for the two 512x512 out-proj weights
__global__ void convT_kernel(const float* __restrict__ a, const float* __restrict__ b,
                             __hip_bfloat16* __restrict__ ta, __hip_bfloat16* __restrict__ tb)
{
  int idx = blockIdx.x * 256 + threadIdx.x;  // 0..524287
  const float* s = a; __hip_bfloat16* d = ta;
  if (idx >= 262144) { s = b; d = tb; idx -= 262144; }
  int i = idx >> 9, j = idx & 511;
  d[i * 512 + j] = __float2bfloat16(s[(size_t)j * 512 + i]);
}

// interleave gate/trans weights; route slices
__global__ void build_gt_kernel(const float* __restrict__ gw, const float* __restrict__ tw,
                                const float* __restrict__ gb, const float* __restrict__ tb,
                                __hip_bfloat16* __restrict__ Wf, __hip_bfloat16* __restrict__ Whin,
                                __hip_bfloat16* __restrict__ Wsin, float* __restrict__ bias)
{
  int idx = blockIdx.x * 256 + threadIdx.x;  // 0..2097151
  int s = idx >> 11, c = idx & 2047;
  int q = s >> 5, r = s & 31;
  float v = (r < 16) ? gw[(size_t)(q * 16 + r) * 2048 + c]
                     : tw[(size_t)(q * 16 + r - 16) * 2048 + c];
  __hip_bfloat16 hv = __float2bfloat16(v);
  if      (c <  512) Wf[(size_t)s * 2048 + c] = hv;
  else if (c < 1024) Whin[(size_t)s * 512 + (c - 512)] = hv;
  else if (c < 1536) Wf[(size_t)s * 2048 + (c - 512)] = hv;
  else               Wsin[(size_t)s * 512 + (c - 1536)] = hv;
  if (c == 0) bias[s] = (r < 16) ? gb[q * 16 + r] : tb[q * 16 + r - 16];
}

// bias folds: bias_gt[s] += Whin[s,:].hout_b ; fvec[s] = Wsin[s,:].sout_b
__global__ __launch_bounds__(256)
void foldbias_kernel(const __hip_bfloat16* __restrict__ Whin, const __hip_bfloat16* __restrict__ Wsin,
                     const float* __restrict__ hob, const float* __restrict__ sob,
                     float* __restrict__ bias_gt, float* __restrict__ fvec)
{
  const int s = blockIdx.x * 256 + threadIdx.x;  // 0..1023
  float a = 0.f, c = 0.f;
  for (int j = 0; j < 512; j += 8) {
    bf16x8 wh = *(const bf16x8*)(Whin + (size_t)s * 512 + j);
    bf16x8 wsv = *(const bf16x8*)(Wsin + (size_t)s * 512 + j);
#pragma unroll
    for (int u = 0; u < 8; ++u) {
      a += (float)wh[u] * hob[j + u];
      c += (float)wsv[u] * sob[j + u];
    }
  }
  bias_gt[s] += a;
  fvec[s] = c;
}

__global__ __launch_bounds__(64)
void ln_kernel(const float* __restrict__ H, const float* __restrict__ U,
               const float* __restrict__ g, const float* __restrict__ bta,
               float* __restrict__ out)
{
  const int row = blockIdx.x, l = threadIdx.x;
  const size_t hb = (size_t)row * 512;
  float x[8];
  float sum = 0.f;
#pragma unroll
  for (int u = 0; u < 8; ++u) {
    int d = u * 64 + l;
    float val = H[hb + d] + U[hb + d];
    x[u] = val; sum += val;
  }
#pragma unroll
  for (int m = 32; m; m >>= 1) sum += __shfl_xor(sum, m);
  float mean = sum * (1.f / 512.f);
  float vs = 0.f;
#pragma unroll
  for (int u = 0; u < 8; ++u) { float d0 = x[u] - mean; vs += d0 * d0; }
#pragma unroll
  for (int m = 32; m; m >>= 1) vs += __shfl_xor(vs, m);
  float rstd = rsqrtf(vs * (1.f / 512.f) + 1e-5f);
#pragma unroll
  for (int u = 0; u < 8; ++u) {
    int d = u * 64 + l;
    out[hb + d] = (x[u] - mean) * rstd * g[d] + bta[d];
  }
}

extern "C" void kernel_launch(void* const* d_in, const int* in_sizes, int n_in,
                              void* d_out, int out_size, void* d_ws, size_t ws_size,
                              hipStream_t stream)
{
  (void)in_sizes; (void)n_in; (void)out_size; (void)ws_size;
  const float* H      = (const float*)d_in[0];
  const int*  pred    = (const int*)d_in[1];
  const int*  maskp   = (const int*)d_in[2];
  const float* hin_w  = (const float*)d_in[3];
  const float* hin_b  = (const float*)d_in[4];
  const float* hout_w = (const float*)d_in[5];
  const float* hout_b = (const float*)d_in[6];
  const float* sin_w  = (const float*)d_in[7];
  const float* sin_b  = (const float*)d_in[8];
  const float* sout_w = (const float*)d_in[9];
  const float* sout_b = (const float*)d_in[10];
  const float* ch_w   = (const float*)d_in[11];
  const float* ch_b   = (const float*)d_in[12];
  const float* g_w    = (const float*)d_in[13];
  const float* g_b    = (const float*)d_in[14];
  const float* t_w    = (const float*)d_in[15];
  const float* t_b    = (const float*)d_in[16];
  const float* lng    = (const float*)d_in[17];
  const float* lnb    = (const float*)d_in[18];

  char* ws = (char*)d_ws;
  __hip_bfloat16* Wqkv  = (__hip_bfloat16*)(ws + 0);          // 3072x512
  __hip_bfloat16* Wch   = (__hip_bfloat16*)(ws + 3145728);    // 512x1024
  __hip_bfloat16* Wgt   = (__hip_bfloat16*)(ws + 4194304);    // 1024x2048 (interleaved)
  float* bias_qkv       = (float*)(ws + 8388608);             // 3072
  float* bias_gt        = (float*)(ws + 8400896);             // 1024
  float* fvec           = (float*)(ws + 8404992);             // 1024
  float* flags          = (float*)(ws + 8409088);             // 16384
  __hip_bfloat16* Hbf   = (__hip_bfloat16*)(ws + 8474624);    // 16384x512
  char* QKVr            = ws + 25251840;                      // big region
  __hip_bfloat16* QKV   = (__hip_bfloat16*)QKVr;              // 16384x3072
  __hip_bfloat16* Whin  = (__hip_bfloat16*)(QKVr + 0);        // 1024x512 (pre-QKV)
  __hip_bfloat16* Wsin  = (__hip_bfloat16*)(QKVr + 1048576);  // 1024x512
  __hip_bfloat16* WhoT  = (__hip_bfloat16*)(QKVr + 2097152);  // 512x512
  __hip_bfloat16* WsoT  = (__hip_bfloat16*)(QKVr + 2621440);  // 512x512
  __hip_bfloat16* CHM   = (__hip_bfloat16*)(QKVr + 0);           // 16384x512 (post-attn)
  float* U              = (float*)(QKVr + 16777216);             // 16384x512 fp32
  __hip_bfloat16* Cavg  = (__hip_bfloat16*)(QKVr + 50331648);    // 16384x512
  __hip_bfloat16* CM2   = (__hip_bfloat16*)(ws + 125915136);  // 16384x1024 [Ohead|Osib]

  hipFuncSetAttribute(reinterpret_cast<const void*>(gemm8_kernel<0>),
                      hipFuncAttributeMaxDynamicSharedMemorySize, 131072);
  hipFuncSetAttribute(reinterpret_cast<const void*>(gemm8_kernel<2>),
                      hipFuncAttributeMaxDynamicSharedMemorySize, 131072);

  // conversions: hin_w, sin_w -> Wqkv; ch_w -> Wch; H -> Hbf
  conv_all_kernel<<<10240, 256, 0, stream>>>(hin_w, sin_w, ch_w, H,
                                             Wqkv, Wqkv + 786432, Wch, Hbf);
  build_gt_kernel<<<8192, 256, 0, stream>>>(g_w, t_w, g_b, t_b, Wgt, Whin, Wsin, bias_gt);
  convT_kernel<<<2048, 256, 0, stream>>>(hout_w, sout_w, WhoT, WsoT);
  foldbias_kernel<<<4, 256, 0, stream>>>(Whin, Wsin, hout_b, sout_b, bias_gt, fvec);
  hipMemcpyAsync(bias_qkv, hin_b, 1536 * 4, hipMemcpyDeviceToDevice, stream);
  hipMemcpyAsync(bias_qkv + 1536, sin_b, 1536 * 4, hipMemcpyDeviceToDevice, stream);

  // weight folds: Wgt[:,1024:1536] = Whin @ WhoT^T ; Wgt[:,1536:2048] = Wsin @ WsoT^T
  gemm_kernel<0, true><<<dim3(4, 8), 256, 0, stream>>>(
      Whin, 512, Whin, 512, Whin, 512, 512, 512, WhoT, 512,
      (const float*)nullptr, (const float*)nullptr, (const float*)nullptr,
      (void*)(Wgt + 1024), 2048, 512);
  gemm_kernel<0, true><<<dim3(4, 8), 256, 0, stream>>>(
      Wsin, 512, Wsin, 512, Wsin, 512, 512, 512, WsoT, 512,
      (const float*)nullptr, (const float*)nullptr, (const float*)nullptr,
      (void*)(Wgt + 1536), 2048, 512);

  // fused QKV projection (8-wave 256x256 pipelined)
  gemm8_kernel<0><<<dim3(12, 64), 512, 131072, stream>>>(
      Hbf, 512, Hbf, 512, Hbf, 512, 512, 512, Wqkv, 512,
      bias_qkv, (const float*)nullptr, (const float*)nullptr,
      (void*)QKV, 3072, 512);

  // attention -> CM2 slices
  attn_kernel<false><<<1024, 256, 0, stream>>>(QKV, pred, maskp, CM2, 1024, flags, 0);
  attn_kernel<true><<<1024, 256, 0, stream>>>(QKV, pred, maskp, CM2 + 512, 1024, flags, 1536);

  // child aggregation + child message GEMM (QKV dead now)
  child_kernel<<<dim3(8, 128), 256, 0, stream>>>(H, pred, maskp, Cavg);
  gemm_kernel<1, true><<<dim3(4, 128), 256, 0, stream>>>(
      Hbf, 512, Cavg, 512, Cavg, 512, 512, 1024, Wch, 1024,
      ch_b, (const float*)nullptr, (const float*)nullptr,
      (void*)CHM, 512, 1024);

  // fused gate/trans GEMM (8-wave pipelined) over virtual comb = [Hbf | CHM | CM2]
  gemm8_kernel<2><<<dim3(4, 64), 512, 131072, stream>>>(
      Hbf, 512, CHM, 512, CM2, 1024, 512, 1024, Wgt, 2048,
      bias_gt, fvec, flags, (void*)U, 512, 2048);

  // residual + layernorm -> d_out
  ln_kernel<<<16384, 64, 0, stream>>>(H, U, lng, lnb, (float*)d_out);
}